// Round 4
// baseline (79.062 us; speedup 1.0000x reference)
//
#include <hip/hip_runtime.h>
#include <hip/hip_bf16.h>

// Problem constants (from reference)
#define BATCH    4096
#define IN_DIM   256
#define OUT_DIM  512
#define KDIM     512       // concat K: [silu(x) | spline(x)]
#define NKNOTS   64
#define NBASIS   60        // NUM_KNOTS - DEGREE - 1

typedef __attribute__((ext_vector_type(8))) short bf16x8;   // 8 bf16 in 4 VGPRs
typedef __attribute__((ext_vector_type(4))) float f32x4;

// Module-scope staging buffers (allocated at load). The harness poisons d_ws
// with a 256 MB fill EVERY iteration regardless of use (~41 us, unconditional
// floor) — device globals sidestep nothing but are simple and race-free.
// Cross-kernel ordering comes free from stream launch order.
__device__ __align__(16) short g_A [BATCH   * KDIM];   // 4 MB bf16
__device__ __align__(16) short g_Bt[OUT_DIM * KDIM];   // 0.5 MB bf16

__device__ __forceinline__ short f2bf(float f) {
    __hip_bfloat16 h = __float2bfloat16(f);
    return *reinterpret_cast<short*>(&h);
}

// ---------------------------------------------------------------------------
// Kernel 1 (prep), 512 blocks (exactly 2 dispatch rounds at 2 blocks/CU —
// r3 post-mortem: the old 576-block grid paid a third partial round for the
// 64 Bt blocks). Every block does its A-share (8 rows); blocks 0..63 ALSO do
// one 64x64 Bt-transpose tile afterwards (concurrent with round-1 A work).
// ---------------------------------------------------------------------------
#define NBLK_PREP 512

__global__ __launch_bounds__(256) void prep_kernel(
        const float* __restrict__ x, const float* __restrict__ wb,
        const float* __restrict__ ws, const float* __restrict__ cps) {
    __shared__ float T[64][65];   // +1 pad: conflict-free column reads

    // ---- A-share: silu | spline, 8 consecutive i per thread, vectorized ----
    {
        const int g  = blockIdx.x * 256 + threadIdx.x;
        const int b  = g >> 5;                      // batch row
        const int i0 = (g & 31) << 3;               // input-dim start
        float xv[8];
        *(f32x4*)&xv[0] = *(const f32x4*)&x[b * IN_DIM + i0];
        *(f32x4*)&xv[4] = *(const f32x4*)&x[b * IN_DIM + i0 + 4];
        bf16x8 sil, spl;
        #pragma unroll
        for (int e = 0; e < 8; ++e) {
            float v = xv[e];
            float s = v / (1.0f + __expf(-v));      // silu
            // uniform cubic B-spline, knots = linspace(-1,1,64), h = 2/63
            float u  = (v + 1.0f) * 31.5f;
            float fj = floorf(u);
            int   j  = (int)fj;
            float sp = 0.0f;
            if (j >= 0 && j <= 62) {
                float t  = u - fj;                  // exact: (v - knots[j])/h
                float t2 = t * t, t3 = t2 * t;
                float omt = 1.0f - t;
                const float c6 = 1.0f / 6.0f;
                float w0 = omt * omt * omt * c6;                       // k0
                float w1 = (3.0f*t3 - 6.0f*t2 + 4.0f) * c6;            // k0+1
                float w2 = (-3.0f*t3 + 3.0f*t2 + 3.0f*t + 1.0f) * c6;  // k0+2
                float w3 = t3 * c6;                                    // k0+3
                const float* cp = cps + (i0 + e) * NKNOTS;
                int k0 = j - 3;
                // reference truncates basis to [0, NBASIS) — mask edges
                if (k0     >= 0 && k0     < NBASIS) sp += w0 * cp[k0];
                if (k0 + 1 >= 0 && k0 + 1 < NBASIS) sp += w1 * cp[k0 + 1];
                if (k0 + 2 >= 0 && k0 + 2 < NBASIS) sp += w2 * cp[k0 + 2];
                if (               k0 + 3 < NBASIS) sp += w3 * cp[k0 + 3];
            }
            sil[e] = f2bf(s);
            spl[e] = f2bf(sp);
        }
        *(bf16x8*)&g_A[b * KDIM + i0]          = sil;
        *(bf16x8*)&g_A[b * KDIM + IN_DIM + i0] = spl;
    }

    // ---- Bt-share (blocks 0..63): LDS-transpose one 64(k) x 64(n) tile ----
    if (blockIdx.x < 64) {
        const int bb = blockIdx.x;
        const int k0 = (bb >> 3) * 64;              // K-tile (concat axis)
        const int n0 = (bb & 7) * 64;               // N-tile
        // 256 % 64 == 0: whole tile comes from one source matrix
        const float* W = (k0 < IN_DIM) ? wb + (size_t)k0 * OUT_DIM
                                       : ws + (size_t)(k0 - IN_DIM) * OUT_DIM;
        const int t  = threadIdx.x;
        const int r  = t >> 2;                      // 0..63
        const int c0 = (t & 3) * 16;                // 16-elem chunk
        #pragma unroll
        for (int e = 0; e < 16; e += 4) {           // 64B contiguous per thread
            f32x4 v = *(const f32x4*)&W[r * OUT_DIM + n0 + c0 + e];
            T[r][c0 + e + 0] = v[0];
            T[r][c0 + e + 1] = v[1];
            T[r][c0 + e + 2] = v[2];
            T[r][c0 + e + 3] = v[3];
        }
        __syncthreads();
        // read transposed column (pad 65 -> conflict-free)
        short tmp[16];
        #pragma unroll
        for (int e = 0; e < 16; ++e) tmp[e] = f2bf(T[c0 + e][r]);
        *(bf16x8*)&g_Bt[(n0 + r) * KDIM + k0 + c0]     = *(bf16x8*)&tmp[0];
        *(bf16x8*)&g_Bt[(n0 + r) * KDIM + k0 + c0 + 8] = *(bf16x8*)&tmp[8];
    }
}

// ---------------------------------------------------------------------------
// Kernel 2: C[4096,512] = A @ Bt^T. 64x64 tile, 4 waves of 32x32, BK=128,
// DOUBLE-BUFFERED LDS + register prefetch (T14 async-stage): step t+1's 8
// global loads are issued before step t's MFMA, so L2/L3 latency hides under
// compute; one barrier per K-step (4 total, was 8).
// LDSS=136: row stride 272B, 16B-aligned; row-pair 2-way bank alias = free.
// LDS = 2 bufs x (As+Bs) = 68 KB/block -> still 2 blocks/CU (136 < 160 KB).
// ---------------------------------------------------------------------------
#define BM 64
#define BN 64
#define BK 128
#define LDSS 136

__global__ __launch_bounds__(256) void gemm_kernel(float* __restrict__ C) {
    __shared__ __align__(16) short As[2][BM * LDSS];
    __shared__ __align__(16) short Bs[2][BN * LDSS];

    const int bid  = blockIdx.x;                    // 512 blocks, 512 % 8 == 0
    const int sbid = (bid & 7) * 64 + (bid >> 3);   // bijective XCD swizzle
    const int m0   = (sbid >> 3) * 64;
    const int n0   = (sbid & 7) * 64;
    const int tid  = threadIdx.x;
    const int lane = tid & 63;
    const int wave = tid >> 6;
    const int wm   = (wave & 1) * 32;               // wave's 32x32 quadrant
    const int wn   = (wave >> 1) * 32;
    const int fr   = lane & 15;                     // fragment row/col index
    const int koff = (lane >> 4) * 8;               // k offset within MFMA K=32

    // staging map: tile = 64 rows x 16 chunks(16B) = 1024 chunks; 4/thread
    const int r_st = tid >> 4;            // rows 0..15 (+16 per s)
    const int o_st = (tid & 15) * 8;      // elem offset within row

    uint4 ra[4], rb[4];
    #pragma unroll
    for (int s = 0; s < 4; ++s) {
        const int r = r_st + s * 16;
        ra[s] = *(const uint4*)&g_A [(m0 + r) * KDIM + o_st];
        rb[s] = *(const uint4*)&g_Bt[(n0 + r) * KDIM + o_st];
    }
    #pragma unroll
    for (int s = 0; s < 4; ++s) {
        const int r = r_st + s * 16;
        *(uint4*)&As[0][r * LDSS + o_st] = ra[s];
        *(uint4*)&Bs[0][r * LDSS + o_st] = rb[s];
    }
    __syncthreads();

    f32x4 acc[2][2] = {};

    #pragma unroll
    for (int t = 0; t < 4; ++t) {
        const int cur = t & 1;
        // issue next step's loads early: latency hides under MFMA below
        if (t < 3) {
            const int k0 = (t + 1) * BK;
            #pragma unroll
            for (int s = 0; s < 4; ++s) {
                const int r = r_st + s * 16;
                ra[s] = *(const uint4*)&g_A [(m0 + r) * KDIM + k0 + o_st];
                rb[s] = *(const uint4*)&g_Bt[(n0 + r) * KDIM + k0 + o_st];
            }
        }

        #pragma unroll
        for (int kk = 0; kk < BK; kk += 32) {
            bf16x8 a0 = *(const bf16x8*)&As[cur][(wm + fr)      * LDSS + kk + koff];
            bf16x8 a1 = *(const bf16x8*)&As[cur][(wm + 16 + fr) * LDSS + kk + koff];
            bf16x8 b0 = *(const bf16x8*)&Bs[cur][(wn + fr)      * LDSS + kk + koff];
            bf16x8 b1 = *(const bf16x8*)&Bs[cur][(wn + 16 + fr) * LDSS + kk + koff];
            acc[0][0] = __builtin_amdgcn_mfma_f32_16x16x32_bf16(a0, b0, acc[0][0], 0, 0, 0);
            acc[0][1] = __builtin_amdgcn_mfma_f32_16x16x32_bf16(a0, b1, acc[0][1], 0, 0, 0);
            acc[1][0] = __builtin_amdgcn_mfma_f32_16x16x32_bf16(a1, b0, acc[1][0], 0, 0, 0);
            acc[1][1] = __builtin_amdgcn_mfma_f32_16x16x32_bf16(a1, b1, acc[1][1], 0, 0, 0);
        }

        if (t < 3) {
            const int nxt = cur ^ 1;
            #pragma unroll
            for (int s = 0; s < 4; ++s) {
                const int r = r_st + s * 16;
                *(uint4*)&As[nxt][r * LDSS + o_st] = ra[s];
                *(uint4*)&Bs[nxt][r * LDSS + o_st] = rb[s];
            }
            __syncthreads();   // nxt ready; also fences reads of cur before
        }                      // it is overwritten two steps later
    }

    // epilogue: C/D layout col = lane&15, row = (lane>>4)*4 + reg  [m89-verified]
    const int rbase = (lane >> 4) * 4;
    #pragma unroll
    for (int mt = 0; mt < 2; ++mt) {
        #pragma unroll
        for (int nt = 0; nt < 2; ++nt) {
            #pragma unroll
            for (int r = 0; r < 4; ++r) {
                int row = m0 + wm + mt * 16 + rbase + r;
                int col = n0 + wn + nt * 16 + fr;
                C[row * OUT_DIM + col] = acc[mt][nt][r];
            }
        }
    }
}

// ---------------------------------------------------------------------------
extern "C" void kernel_launch(void* const* d_in, const int* in_sizes, int n_in,
                              void* d_out, int out_size, void* d_ws, size_t ws_size,
                              hipStream_t stream) {
    (void)in_sizes; (void)n_in; (void)d_ws; (void)ws_size; (void)out_size;
    const float* x   = (const float*)d_in[0];
    const float* wb  = (const float*)d_in[1];
    const float* wsp = (const float*)d_in[2];
    const float* cps = (const float*)d_in[3];
    // d_in[4] = knots: uniform, closed-form basis — values not needed
    float* out = (float*)d_out;

    prep_kernel<<<NBLK_PREP, 256, 0, stream>>>(x, wb, wsp, cps);
    gemm_kernel<<<512, 256, 0, stream>>>(out);
}